// Round 1
// baseline (334.306 us; speedup 1.0000x reference)
//
#include <hip/hip_runtime.h>

#define NB 1000000
#define NA 40
#define TILE 256
#define NTILES ((NB + TILE - 1) / TILE)   // 3907

// Each block handles a tile of 256 samples x 40 attrs.
// targets staged to LDS as packed bytes (row stride 260 B -> <=2-way bank conflicts, free).
// inputs read directly as float4 (40 % 4 == 0, never straddles a sample row).
__global__ __launch_bounds__(256) void focal_loss_kernel(
    const float* __restrict__ inputs,    // [NB, NA] f32
    const int*   __restrict__ targets,   // [NA, NB] i32 in {0,1}
    const float* __restrict__ attr_w,    // [NA] f32
    float* __restrict__ out)             // [1] f32 (pre-zeroed)
{
    __shared__ unsigned int s_t[NA * 65];      // [40][65] u32 = [40][260] bytes
    __shared__ float s_aw[NA];
    __shared__ float s_red[TILE / 64];

    const int t  = threadIdx.x;
    const int b0 = blockIdx.x * TILE;

    // stage weights, pre-folded with -ln2/40 (bce = -ln2*log2(sel); mean over A=40)
    if (t < NA) s_aw[t] = attr_w[t] * (-0.017328679513998632f);

    // --- stage targets: 10 int4 loads/thread; each wave covers exactly one attr row ---
    #pragma unroll
    for (int j = 0; j < 10; ++j) {
        const int q    = t + TILE * j;   // [0, 2560)
        const int a    = q >> 6;         // attr 0..39
        const int t4   = q & 63;         // int4 index within row
        const int base = b0 + 4 * t4;
        unsigned int pack = 0;
        if (base + 3 < NB) {
            const int4 v = *(const int4*)(targets + (size_t)a * NB + base);
            pack =  (unsigned)(v.x & 1)        | ((unsigned)(v.y & 1) << 8)
                 | ((unsigned)(v.z & 1) << 16) | ((unsigned)(v.w & 1) << 24);
        } else {
            for (int k = 0; k < 4; ++k)
                if (base + k < NB)
                    pack |= (unsigned)(targets[(size_t)a * NB + base + k] & 1) << (8 * k);
        }
        s_t[a * 65 + t4] = pack;
    }
    __syncthreads();

    const unsigned char* st8 = (const unsigned char*)s_t;
    const float4* in4 = (const float4*)inputs + (size_t)b0 * 10;

    float acc = 0.0f;
    #pragma unroll
    for (int j = 0; j < 10; ++j) {
        const int f = t + TILE * j;      // float4 index within tile [0, 2560)
        const int s = f / 10;            // sample within tile
        const int r = 4 * (f - s * 10);  // attr base (0,4,...,36)
        if (b0 + s < NB) {
            const float4 x4 = in4[f];
            const float xs[4] = {x4.x, x4.y, x4.z, x4.w};
            #pragma unroll
            for (int k = 0; k < 4; ++k) {
                const int a = r + k;
                const float x   = xs[k];
                const float om  = 1.0f - x;               // exact for x>=0.5; fine below
                const float w   = s_aw[a] * (om * om);    // -ln2/40 * aw * (1-x)^2
                const float p   = fmaxf(x,  1e-12f);      // clip low (1-eps rounds to 1.0f anyway)
                const float q0  = fmaxf(om, 1e-12f);
                const float sel = st8[a * 260 + s] ? p : q0;
                acc = fmaf(w, __log2f(sel), acc);         // w<0, log2(sel)<=0 -> positive loss
            }
        }
    }

    // --- reduce: 64-lane wave shuffle, then cross-wave via LDS, one atomic/block ---
    float v = acc;
    #pragma unroll
    for (int off = 32; off > 0; off >>= 1)
        v += __shfl_xor(v, off, 64);
    if ((t & 63) == 0) s_red[t >> 6] = v;
    __syncthreads();
    if (t == 0) {
        float r2 = 0.0f;
        #pragma unroll
        for (int w2 = 0; w2 < TILE / 64; ++w2) r2 += s_red[w2];
        atomicAdd(out, r2);
    }
}

extern "C" void kernel_launch(void* const* d_in, const int* in_sizes, int n_in,
                              void* d_out, int out_size, void* d_ws, size_t ws_size,
                              hipStream_t stream) {
    const float* inputs  = (const float*)d_in[0];
    const int*   targets = (const int*)d_in[1];
    const float* attr_w  = (const float*)d_in[2];
    float* out = (float*)d_out;
    hipMemsetAsync(out, 0, sizeof(float), stream);  // graph-capturable memset node
    focal_loss_kernel<<<dim3(NTILES), dim3(TILE), 0, stream>>>(inputs, targets, attr_w, out);
}

// Round 2
// 324.664 us; speedup vs baseline: 1.0297x; 1.0297x over previous
//
#include <hip/hip_runtime.h>

#define NB 1000000
#define NA 40
#define TILE 256
#define NTILES ((NB + TILE - 1) / TILE)   // 3907
#define NEG_LN2_OVER_A (-0.017328679513998632f)  // -ln(2)/40, folded into weights

// Block = 256 samples x 40 attrs. Targets staged to LDS attr-major, 4 labels
// packed per u32, row stride 65 words (260 B) -> staging writes conflict-free,
// compute byte-reads ~2-way (measured 1.25e6 conflicts total = negligible).
// Key round-2 change: loads batched into register arrays for MLP — round 1's
// VGPR_Count=16 meant one outstanding load/wave -> latency-bound at 126 us.
__global__ __launch_bounds__(256) void focal_loss_kernel(
    const float* __restrict__ inputs,    // [NB, NA] f32
    const int*   __restrict__ targets,   // [NA, NB] i32 in {0,1}
    const float* __restrict__ attr_w,    // [NA] f32
    float* __restrict__ out)             // [1] f32 (pre-zeroed)
{
    __shared__ unsigned int s_t[NA * 65];      // [40][65] u32 = [40][260] bytes
    __shared__ float s_aw[NA];
    __shared__ float s_red[TILE / 64];

    const int t  = threadIdx.x;
    const int b0 = blockIdx.x * TILE;

    if (t < NA) s_aw[t] = attr_w[t] * NEG_LN2_OVER_A;

    float acc = 0.0f;

    if (blockIdx.x != NTILES - 1) {
        // ================= fast path: full tile, no per-element guards ======
        // ---- issue ALL target loads, then ALL input loads (20 in flight) ---
        int4 v[10];
        #pragma unroll
        for (int j = 0; j < 10; ++j) {
            const int q  = t + TILE * j;   // [0, 2560)
            const int a  = q >> 6;         // attr 0..39
            const int t4 = q & 63;         // int4 index within row
            v[j] = *(const int4*)(targets + (size_t)a * NB + (b0 + 4 * t4));
        }
        const float4* in4 = (const float4*)inputs + (size_t)b0 * 10;
        float4 xv[10];
        #pragma unroll
        for (int j = 0; j < 10; ++j) xv[j] = in4[t + TILE * j];

        // ---- pack labels -> LDS (waits vmcnt for v[] only; xv streams on) --
        #pragma unroll
        for (int j = 0; j < 10; ++j) {
            const int q  = t + TILE * j;
            const int a  = q >> 6;
            const int t4 = q & 63;
            s_t[a * 65 + t4] =  (unsigned)(v[j].x & 1)        | ((unsigned)(v[j].y & 1) << 8)
                             | ((unsigned)(v[j].z & 1) << 16) | ((unsigned)(v[j].w & 1) << 24);
        }
        __syncthreads();

        // ---- compute ----
        const unsigned char* st8 = (const unsigned char*)s_t;
        #pragma unroll
        for (int j = 0; j < 10; ++j) {
            const int f = t + TILE * j;
            const int s = f / 10;            // sample within tile
            const int r = 4 * (f - s * 10);  // attr base (0,4,...,36)
            const float xs[4] = {xv[j].x, xv[j].y, xv[j].z, xv[j].w};
            #pragma unroll
            for (int k = 0; k < 4; ++k) {
                const float x   = xs[k];
                const float om  = 1.0f - x;
                const float w   = s_aw[r + k] * (om * om);   // -ln2/40*aw*(1-x)^2
                const float p   = fmaxf(x,  1e-12f);
                const float q0  = fmaxf(om, 1e-12f);
                const float sel = st8[(r + k) * 260 + s] ? p : q0;
                acc = fmaf(w, __log2f(sel), acc);            // w<0, log2<=0 -> positive
            }
        }
    } else {
        // ================= tail block (64 valid samples): guarded ===========
        #pragma unroll
        for (int j = 0; j < 10; ++j) {
            const int q  = t + TILE * j;
            const int a  = q >> 6;
            const int t4 = q & 63;
            const int base = b0 + 4 * t4;
            unsigned int pack = 0;
            for (int k = 0; k < 4; ++k)
                if (base + k < NB)
                    pack |= (unsigned)(targets[(size_t)a * NB + base + k] & 1) << (8 * k);
            s_t[a * 65 + t4] = pack;
        }
        __syncthreads();
        const unsigned char* st8 = (const unsigned char*)s_t;
        const float4* in4 = (const float4*)inputs + (size_t)b0 * 10;
        #pragma unroll
        for (int j = 0; j < 10; ++j) {
            const int f = t + TILE * j;
            const int s = f / 10;
            const int r = 4 * (f - s * 10);
            if (b0 + s < NB) {
                const float4 x4 = in4[f];
                const float xs[4] = {x4.x, x4.y, x4.z, x4.w};
                #pragma unroll
                for (int k = 0; k < 4; ++k) {
                    const float x   = xs[k];
                    const float om  = 1.0f - x;
                    const float w   = s_aw[r + k] * (om * om);
                    const float p   = fmaxf(x,  1e-12f);
                    const float q0  = fmaxf(om, 1e-12f);
                    const float sel = st8[(r + k) * 260 + s] ? p : q0;
                    acc = fmaf(w, __log2f(sel), acc);
                }
            }
        }
    }

    // ---- reduce: 64-lane shuffle -> cross-wave LDS -> one atomic/block ----
    float vsum = acc;
    #pragma unroll
    for (int off = 32; off > 0; off >>= 1)
        vsum += __shfl_xor(vsum, off, 64);
    if ((t & 63) == 0) s_red[t >> 6] = vsum;
    __syncthreads();
    if (t == 0) {
        float r2 = 0.0f;
        #pragma unroll
        for (int w2 = 0; w2 < TILE / 64; ++w2) r2 += s_red[w2];
        atomicAdd(out, r2);
    }
}

extern "C" void kernel_launch(void* const* d_in, const int* in_sizes, int n_in,
                              void* d_out, int out_size, void* d_ws, size_t ws_size,
                              hipStream_t stream) {
    const float* inputs  = (const float*)d_in[0];
    const int*   targets = (const int*)d_in[1];
    const float* attr_w  = (const float*)d_in[2];
    float* out = (float*)d_out;
    hipMemsetAsync(out, 0, sizeof(float), stream);
    focal_loss_kernel<<<dim3(NTILES), dim3(TILE), 0, stream>>>(inputs, targets, attr_w, out);
}